// Round 11
// baseline (230.277 us; speedup 1.0000x reference)
//
#include <hip/hip_runtime.h>
#include <math.h>

#define B_   8
#define N_   2048
#define IN_  256
#define H_   4
#define D_   64
#define C_   256            // H_*D_
#define M_   (B_*N_)        // 16384
#define NEG  0.2f
#define LOG2E 1.4426950408889634f

typedef short bf16x8 __attribute__((ext_vector_type(8)));
typedef float f32x4  __attribute__((ext_vector_type(4)));

__device__ inline ushort f32_to_bf16_rne(float x) {
    union { float f; unsigned u; } c; c.f = x;
    unsigned u = c.u + 0x7FFFu + ((c.u >> 16) & 1u);
    return (ushort)(u >> 16);
}
__device__ inline float bf16_hi_to_f32(ushort u) {
    union { unsigned u; float f; } c; c.u = ((unsigned)u) << 16;
    return c.f;
}
__device__ inline void split8(const float v[8], bf16x8* hi, bf16x8* lo) {
    union { bf16x8 v; ushort u[8]; } H, L;
    #pragma unroll
    for (int j = 0; j < 8; j++) {
        ushort hb = f32_to_bf16_rne(v[j]);
        H.u[j] = hb;
        L.u[j] = f32_to_bf16_rne(v[j] - bf16_hi_to_f32(hb));
    }
    *hi = H.v; *lo = L.v;
}

// ---------------------------------------------------------------------------
// K0 wprep: Wt_hi/Wt_lo[c][k] = split-cast transposed W (64 blocks).
// ---------------------------------------------------------------------------
__global__ __launch_bounds__(256) void wprep_kernel(const float* __restrict__ W,
                                                    ushort* __restrict__ Wt_hi,
                                                    ushort* __restrict__ Wt_lo) {
    const int t = threadIdx.x, blk = blockIdx.x;
    ushort his[4], los[4];
    #pragma unroll
    for (int kk = 0; kk < 4; kk++) {
        float v = W[(blk * 4 + kk) * 256 + t];
        ushort hi = f32_to_bf16_rne(v);
        his[kk] = hi;
        los[kk] = f32_to_bf16_rne(v - bf16_hi_to_f32(hi));
    }
    *(uint2*)&Wt_hi[(size_t)t * 256 + blk * 4] =
        make_uint2(((uint)his[0]) | (((uint)his[1]) << 16), ((uint)his[2]) | (((uint)his[3]) << 16));
    *(uint2*)&Wt_lo[(size_t)t * 256 + blk * 4] =
        make_uint2(((uint)los[0]) | (((uint)los[1]) << 16), ((uint)los[2]) | (((uint)los[3]) << 16));
}

// ---------------------------------------------------------------------------
// K1 gemm_fused: R10's verified barrier-free split-bf16 MFMA loop.
// Epilogue now writes f32 Wh[m][c] directly + log2-domain scores eL/rL.
// Grid (128, 4) = 512 blocks x 256 thr. Block: 128 m x 64 c (one head).
// ---------------------------------------------------------------------------
#define BP 264   // B LDS pitch (ushorts)

__global__ __launch_bounds__(256, 2) void gemm_fused(const float* __restrict__ h,
                                                     const ushort* __restrict__ Wt_hi,
                                                     const ushort* __restrict__ Wt_lo,
                                                     const float* __restrict__ a_src,
                                                     const float* __restrict__ a_dst,
                                                     float* __restrict__ Wh,
                                                     float* __restrict__ eL,
                                                     float* __restrict__ rL) {
    __shared__ ushort Bs_h[64 * BP], Bs_l[64 * BP];

    const int t = threadIdx.x;
    const int m0 = blockIdx.x * 128;
    const int nb = blockIdx.y;                 // head
    const int b  = m0 >> 11;
    const int wid = t >> 6, lane = t & 63;
    const int c16 = lane & 15, quad = lane >> 4;

    // stage B once
    {
        const int c = t >> 2, kq = t & 3;
        const ushort* sh = Wt_hi + (size_t)(nb * 64 + c) * 256 + kq * 64;
        const ushort* sl = Wt_lo + (size_t)(nb * 64 + c) * 256 + kq * 64;
        ushort* dh = &Bs_h[c * BP + kq * 64];
        ushort* dl = &Bs_l[c * BP + kq * 64];
        #pragma unroll
        for (int q = 0; q < 8; q++) {
            *(uint4*)(dh + q * 8) = *(const uint4*)(sh + q * 8);
            *(uint4*)(dl + q * 8) = *(const uint4*)(sl + q * 8);
        }
    }

    const int row0 = m0 + wid * 32 + c16;
    const float* hp0 = h + (size_t)row0 * 256 + quad * 8;
    const float* hp1 = hp0 + 16 * 256;

    float4 p0a = *(const float4*)hp0, p0b = *(const float4*)(hp0 + 4);
    float4 p1a = *(const float4*)hp1, p1b = *(const float4*)(hp1 + 4);

    __syncthreads();                            // B staged

    f32x4 acc[2][4] = {};
    for (int k0 = 0; k0 < 256; k0 += 32) {
        float v0[8] = {p0a.x, p0a.y, p0a.z, p0a.w, p0b.x, p0b.y, p0b.z, p0b.w};
        float v1[8] = {p1a.x, p1a.y, p1a.z, p1a.w, p1b.x, p1b.y, p1b.z, p1b.w};
        if (k0 < 224) {
            p0a = *(const float4*)(hp0 + k0 + 32); p0b = *(const float4*)(hp0 + k0 + 36);
            p1a = *(const float4*)(hp1 + k0 + 32); p1b = *(const float4*)(hp1 + k0 + 36);
        }
        bf16x8 ah0, al0, ah1, al1;
        split8(v0, &ah0, &al0);
        split8(v1, &ah1, &al1);
        #pragma unroll
        for (int fc = 0; fc < 4; fc++) {
            bf16x8 bhf = *(const bf16x8*)&Bs_h[(fc * 16 + c16) * BP + k0 + quad * 8];
            bf16x8 blf = *(const bf16x8*)&Bs_l[(fc * 16 + c16) * BP + k0 + quad * 8];
            acc[0][fc] = __builtin_amdgcn_mfma_f32_16x16x32_bf16(ah0, bhf, acc[0][fc], 0, 0, 0);
            acc[0][fc] = __builtin_amdgcn_mfma_f32_16x16x32_bf16(al0, bhf, acc[0][fc], 0, 0, 0);
            acc[0][fc] = __builtin_amdgcn_mfma_f32_16x16x32_bf16(ah0, blf, acc[0][fc], 0, 0, 0);
            acc[1][fc] = __builtin_amdgcn_mfma_f32_16x16x32_bf16(ah1, bhf, acc[1][fc], 0, 0, 0);
            acc[1][fc] = __builtin_amdgcn_mfma_f32_16x16x32_bf16(al1, bhf, acc[1][fc], 0, 0, 0);
            acc[1][fc] = __builtin_amdgcn_mfma_f32_16x16x32_bf16(ah1, blf, acc[1][fc], 0, 0, 0);
        }
    }

    // scores epilogue: el/er from acc (exact f32), butterfly over c16
    {
        float avs[4], avd[4];
        #pragma unroll
        for (int fc = 0; fc < 4; fc++) {
            avs[fc] = a_src[nb * 64 + fc * 16 + c16];
            avd[fc] = a_dst[nb * 64 + fc * 16 + c16];
        }
        float ds[2][4] = {}, dd[2][4] = {};
        #pragma unroll
        for (int rw = 0; rw < 2; rw++)
            #pragma unroll
            for (int r = 0; r < 4; r++)
                #pragma unroll
                for (int fc = 0; fc < 4; fc++) {
                    ds[rw][r] += acc[rw][fc][r] * avs[fc];
                    dd[rw][r] += acc[rw][fc][r] * avd[fc];
                }
        #pragma unroll
        for (int off = 1; off < 16; off <<= 1)
            #pragma unroll
            for (int rw = 0; rw < 2; rw++)
                #pragma unroll
                for (int r = 0; r < 4; r++) {
                    ds[rw][r] += __shfl_xor(ds[rw][r], off);
                    dd[rw][r] += __shfl_xor(dd[rw][r], off);
                }
        if (c16 == 0) {
            #pragma unroll
            for (int rw = 0; rw < 2; rw++)
                #pragma unroll
                for (int r = 0; r < 4; r++) {
                    int m = m0 + wid * 32 + rw * 16 + quad * 4 + r;
                    int idx = (b * 4 + nb) * N_ + (m & 2047);
                    eL[idx] = ds[rw][r] * LOG2E;
                    rL[idx] = dd[rw][r] * LOG2E;
                }
        }
    }

    // Wh f32 direct stores (layout [m][c])
    #pragma unroll
    for (int rw = 0; rw < 2; rw++)
        #pragma unroll
        for (int r = 0; r < 4; r++) {
            int n = m0 + wid * 32 + rw * 16 + quad * 4 + r;
            float* dst = Wh + (size_t)n * 256 + nb * 64;
            #pragma unroll
            for (int fc = 0; fc < 4; fc++)
                dst[fc * 16 + c16] = acc[rw][fc][r];
        }
}

// ---------------------------------------------------------------------------
// K2 sort: per bh, bitonic sort of rL ascending (keys + original index).
// Emits r_srt, perm, E_srt = 2^r, F_srt = 2^(0.2 r).
// ---------------------------------------------------------------------------
__global__ __launch_bounds__(256) void sort_kernel(const float* __restrict__ rL,
                                                   float* __restrict__ r_srt,
                                                   int* __restrict__ perm,
                                                   float* __restrict__ E_srt,
                                                   float* __restrict__ F_srt) {
    __shared__ float key[2048];
    __shared__ int   idx[2048];
    const int bh = blockIdx.x, t = threadIdx.x;
    for (int s = t; s < 2048; s += 256) { key[s] = rL[bh * 2048 + s]; idx[s] = s; }
    __syncthreads();
    for (int k = 2; k <= 2048; k <<= 1) {
        for (int j = k >> 1; j > 0; j >>= 1) {
            for (int s = t; s < 2048; s += 256) {
                int p = s ^ j;
                if (p > s) {
                    bool up = ((s & k) == 0);
                    float a = key[s], bq = key[p];
                    bool sw = up ? (a > bq) : (a < bq);
                    if (sw) {
                        key[s] = bq; key[p] = a;
                        int ia = idx[s]; idx[s] = idx[p]; idx[p] = ia;
                    }
                }
            }
            __syncthreads();
        }
    }
    for (int s = t; s < 2048; s += 256) {
        float rv = key[s];
        r_srt[bh * 2048 + s] = rv;
        perm[bh * 2048 + s]  = idx[s];
        E_srt[bh * 2048 + s] = __builtin_amdgcn_exp2f(rv);
        F_srt[bh * 2048 + s] = __builtin_amdgcn_exp2f(NEG * rv);
    }
}

// ---------------------------------------------------------------------------
// K3 chunk sums: per (bh, 32-j chunk): vector sums of F*WhRow and E*WhRow.
// Grid (32, 16), 256 thr = 4 waves, wave = one chunk, lane = d.
// ---------------------------------------------------------------------------
__global__ __launch_bounds__(256) void chunksum_kernel(const float* __restrict__ Wh,
                                                       const int* __restrict__ perm,
                                                       const float* __restrict__ E_srt,
                                                       const float* __restrict__ F_srt,
                                                       float* __restrict__ chunkF,
                                                       float* __restrict__ chunkE,
                                                       float* __restrict__ chunk_sf,
                                                       float* __restrict__ chunk_se) {
    const int bh = blockIdx.x;
    const int b = bh >> 2, hh = bh & 3;
    const int w = threadIdx.x >> 6, lane = threadIdx.x & 63;
    const int ch = blockIdx.y * 4 + w;
    const int j0 = ch * 32;

    float fv = 0.f, ev = 0.f; int pv = 0;
    if (lane < 32) {
        fv = F_srt[bh * 2048 + j0 + lane];
        ev = E_srt[bh * 2048 + j0 + lane];
        pv = perm[bh * 2048 + j0 + lane];
    }
    float v[32];
    #pragma unroll
    for (int jj = 0; jj < 32; jj++) {
        int pj = __shfl(pv, jj);
        v[jj] = Wh[((size_t)(b * 2048 + pj)) * 256 + hh * 64 + lane];
    }
    float aF = 0.f, aE = 0.f, sf = 0.f, se = 0.f;
    #pragma unroll
    for (int jj = 0; jj < 32; jj++) {
        float fj = __shfl(fv, jj), ej = __shfl(ev, jj);
        aF += fj * v[jj]; aE += ej * v[jj];
        sf += fj; se += ej;
    }
    size_t o = ((size_t)bh * 64 + ch) * 64 + lane;
    chunkF[o] = aF; chunkE[o] = aE;
    if (lane == 0) { chunk_sf[bh * 64 + ch] = sf; chunk_se[bh * 64 + ch] = se; }
}

// ---------------------------------------------------------------------------
// K4 scan: per bh (32 blocks x 64 thr): exclusive prefix offsets of chunkF
// (ascending) and exclusive suffix offsets of chunkE (descending). Also the
// t=2048 boundary rows: PF[2048] = total, SES[2048] = 0.
// ---------------------------------------------------------------------------
__global__ __launch_bounds__(64) void scan_kernel(const float* __restrict__ chunkF,
                                                  const float* __restrict__ chunkE,
                                                  const float* __restrict__ chunk_sf,
                                                  const float* __restrict__ chunk_se,
                                                  float* __restrict__ offF,
                                                  float* __restrict__ offE,
                                                  float* __restrict__ offF_s,
                                                  float* __restrict__ offE_s,
                                                  float* __restrict__ PF,
                                                  float* __restrict__ SES,
                                                  float* __restrict__ pf_s,
                                                  float* __restrict__ ses_s) {
    const int bh = blockIdx.x, d = threadIdx.x;
    float accF = 0.f, sF = 0.f;
    for (int c = 0; c < 64; c++) {
        size_t o = ((size_t)bh * 64 + c) * 64 + d;
        offF[o] = accF;
        if (d == 0) offF_s[bh * 64 + c] = sF;
        accF += chunkF[o];
        sF += chunk_sf[bh * 64 + c];
    }
    float accE = 0.f, sE = 0.f;
    for (int c = 63; c >= 0; c--) {
        size_t o = ((size_t)bh * 64 + c) * 64 + d;
        offE[o] = accE;
        if (d == 0) offE_s[bh * 64 + c] = sE;
        accE += chunkE[o];
        sE += chunk_se[bh * 64 + c];
    }
    PF[((size_t)bh * 2049 + 2048) * 64 + d]  = accF;
    SES[((size_t)bh * 2049 + 2048) * 64 + d] = 0.0f;
    if (d == 0) { pf_s[bh * 2049 + 2048] = sF; ses_s[bh * 2049 + 2048] = 0.0f; }
}

// ---------------------------------------------------------------------------
// K5 emit: per (bh, 32-j chunk), 64 thr (lane = d): full PF (exclusive prefix,
// ascending) and SES (inclusive suffix, descending) rows + scalar dens.
// Rows cached in registers (one global read pass).
// ---------------------------------------------------------------------------
__global__ __launch_bounds__(64) void emit_kernel(const float* __restrict__ Wh,
                                                  const int* __restrict__ perm,
                                                  const float* __restrict__ E_srt,
                                                  const float* __restrict__ F_srt,
                                                  const float* __restrict__ offF,
                                                  const float* __restrict__ offE,
                                                  const float* __restrict__ offF_s,
                                                  const float* __restrict__ offE_s,
                                                  float* __restrict__ PF,
                                                  float* __restrict__ SES,
                                                  float* __restrict__ pf_s,
                                                  float* __restrict__ ses_s) {
    const int bh = blockIdx.x, ch = blockIdx.y;
    const int b = bh >> 2, hh = bh & 3;
    const int d = threadIdx.x;
    const int j0 = ch * 32;

    float fv = 0.f, ev = 0.f; int pv = 0;
    if (d < 32) {
        fv = F_srt[bh * 2048 + j0 + d];
        ev = E_srt[bh * 2048 + j0 + d];
        pv = perm[bh * 2048 + j0 + d];
    }
    float v[32];
    #pragma unroll
    for (int jj = 0; jj < 32; jj++) {
        int pj = __shfl(pv, jj);
        v[jj] = Wh[((size_t)(b * 2048 + pj)) * 256 + hh * 64 + d];
    }
    float accF = offF[((size_t)bh * 64 + ch) * 64 + d];
    float sF   = offF_s[bh * 64 + ch];
    #pragma unroll
    for (int jj = 0; jj < 32; jj++) {
        float fj = __shfl(fv, jj);
        size_t ro = ((size_t)bh * 2049 + j0 + jj) * 64 + d;
        PF[ro] = accF;
        if (d == 0) pf_s[bh * 2049 + j0 + jj] = sF;
        accF += fj * v[jj];
        sF += fj;
    }
    float accE = offE[((size_t)bh * 64 + ch) * 64 + d];
    float sE   = offE_s[bh * 64 + ch];
    #pragma unroll
    for (int jj = 31; jj >= 0; jj--) {
        float ej = __shfl(ev, jj);
        accE += ej * v[jj];
        sE += ej;
        size_t ro = ((size_t)bh * 2049 + j0 + jj) * 64 + d;
        SES[ro] = accE;
        if (d == 0) ses_s[bh * 2049 + j0 + jj] = sE;
    }
}

// ---------------------------------------------------------------------------
// K6 final: per (bh, 64-i group): binary-search t_i = lower_bound(r_srt, -e_i)
// (LDS-cached sorted keys), then out row = (G_i*PF[t] + SES[t]) /
// (G_i*pf_s[t] + ses_s[t]) + bias. Wave = 64 lanes = 64 d, coalesced rows.
// ---------------------------------------------------------------------------
__global__ __launch_bounds__(256) void final_kernel(const float* __restrict__ eL,
                                                    const float* __restrict__ r_srt,
                                                    const float* __restrict__ PF,
                                                    const float* __restrict__ SES,
                                                    const float* __restrict__ pf_s,
                                                    const float* __restrict__ ses_s,
                                                    const float* __restrict__ bias,
                                                    float* __restrict__ out) {
    __shared__ float r_sh[2048];
    __shared__ int   t_sh[64];
    __shared__ float g_sh[64];
    const int bh = blockIdx.x, ig = blockIdx.y;
    const int b = bh >> 2, hh = bh & 3;
    const int t = threadIdx.x;

    for (int s = t; s < 2048; s += 256) r_sh[s] = r_srt[bh * 2048 + s];
    __syncthreads();
    if (t < 64) {
        int i = ig * 64 + t;
        float e = eL[bh * 2048 + i];
        float target = -e;
        int lo = 0, hi = 2048;
        while (lo < hi) {
            int mid = (lo + hi) >> 1;
            if (r_sh[mid] < target) lo = mid + 1; else hi = mid;
        }
        t_sh[t] = lo;
        g_sh[t] = __builtin_amdgcn_exp2f(-0.8f * e);
    }
    __syncthreads();

    const int w = t >> 6, lane = t & 63;       // lane = d
    const float bl = bias[hh * 64 + lane];
    #pragma unroll 4
    for (int q = 0; q < 16; q++) {
        int il = w * 16 + q;
        int ti = t_sh[il];
        float G = g_sh[il];
        size_t base = ((size_t)bh * 2049 + ti) * 64 + lane;
        float pf  = PF[base];
        float ses = SES[base];
        float dpf  = pf_s[bh * 2049 + ti];
        float dses = ses_s[bh * 2049 + ti];
        float num = G * pf + ses;
        float den = G * dpf + dses;
        int i = ig * 64 + il;
        out[((size_t)(b * 2048 + i)) * 256 + hh * 64 + lane] = num / den + bl;
    }
}

// ---------------------------------------------------------------------------
extern "C" void kernel_launch(void* const* d_in, const int* in_sizes, int n_in,
                              void* d_out, int out_size, void* d_ws, size_t ws_size,
                              hipStream_t stream) {
    const float* h     = (const float*)d_in[0];
    const float* W     = (const float*)d_in[1];
    const float* a_src = (const float*)d_in[2];
    const float* a_dst = (const float*)d_in[3];
    const float* bias  = (const float*)d_in[4];
    float* out = (float*)d_out;

    float* Wh       = (float*)d_ws;                  // 4,194,304
    float* eL       = Wh + (size_t)M_ * C_;          // 65536
    float* rL       = eL + 32 * N_;
    float* r_srt    = rL + 32 * N_;
    float* E_srt    = r_srt + 32 * N_;
    float* F_srt    = E_srt + 32 * N_;
    float* chunkF   = F_srt + 32 * N_;               // 32*64*64
    float* chunkE   = chunkF + 32 * 64 * 64;
    float* chunk_sf = chunkE + 32 * 64 * 64;         // 2048
    float* chunk_se = chunk_sf + 32 * 64;
    float* offF     = chunk_se + 32 * 64;            // 32*64*64
    float* offE     = offF + 32 * 64 * 64;
    float* offF_s   = offE + 32 * 64 * 64;           // 2048
    float* offE_s   = offF_s + 32 * 64;
    float* PF       = offE_s + 32 * 64;              // 32*2049*64
    float* SES      = PF + (size_t)32 * 2049 * 64;
    float* pf_s     = SES + (size_t)32 * 2049 * 64;  // 32*2049
    float* ses_s    = pf_s + 32 * 2049;
    int*   perm     = (int*)(ses_s + 32 * 2049);     // 65536 ints
    ushort* Wt_hi   = (ushort*)(perm + 32 * N_);     // 65536 ushorts
    ushort* Wt_lo   = Wt_hi + 256 * 256;

    wprep_kernel<<<64, 256, 0, stream>>>(W, Wt_hi, Wt_lo);
    gemm_fused<<<dim3(M_ / 128, 4), 256, 0, stream>>>(h, Wt_hi, Wt_lo, a_src, a_dst,
                                                      Wh, eL, rL);
    sort_kernel<<<32, 256, 0, stream>>>(rL, r_srt, perm, E_srt, F_srt);
    chunksum_kernel<<<dim3(32, 16), 256, 0, stream>>>(Wh, perm, E_srt, F_srt,
                                                      chunkF, chunkE, chunk_sf, chunk_se);
    scan_kernel<<<32, 64, 0, stream>>>(chunkF, chunkE, chunk_sf, chunk_se,
                                       offF, offE, offF_s, offE_s,
                                       PF, SES, pf_s, ses_s);
    emit_kernel<<<dim3(32, 64), 64, 0, stream>>>(Wh, perm, E_srt, F_srt,
                                                 offF, offE, offF_s, offE_s,
                                                 PF, SES, pf_s, ses_s);
    final_kernel<<<dim3(32, 32), 256, 0, stream>>>(eL, r_srt, PF, SES, pf_s, ses_s,
                                                   bias, out);
}

// Round 12
// 143.651 us; speedup vs baseline: 1.6030x; 1.6030x over previous
//
#include <hip/hip_runtime.h>
#include <math.h>

#define B_   8
#define N_   2048
#define IN_  256
#define H_   4
#define D_   64
#define C_   256            // H_*D_
#define M_   (B_*N_)        // 16384
#define NEG  0.2f
#define LOG2E 1.4426950408889634f

typedef short bf16x8 __attribute__((ext_vector_type(8)));
typedef float f32x4  __attribute__((ext_vector_type(4)));

__device__ inline ushort f32_to_bf16_rne(float x) {
    union { float f; unsigned u; } c; c.f = x;
    unsigned u = c.u + 0x7FFFu + ((c.u >> 16) & 1u);
    return (ushort)(u >> 16);
}
__device__ inline float bf16_hi_to_f32(ushort u) {
    union { unsigned u; float f; } c; c.u = ((unsigned)u) << 16;
    return c.f;
}
__device__ inline void split8(const float v[8], bf16x8* hi, bf16x8* lo) {
    union { bf16x8 v; ushort u[8]; } H, L;
    #pragma unroll
    for (int j = 0; j < 8; j++) {
        ushort hb = f32_to_bf16_rne(v[j]);
        H.u[j] = hb;
        L.u[j] = f32_to_bf16_rne(v[j] - bf16_hi_to_f32(hb));
    }
    *hi = H.v; *lo = L.v;
}
// order-preserving float -> uint
__device__ inline uint fenc(float f) {
    uint u = __float_as_uint(f);
    return u ^ (((int)u < 0) ? 0xFFFFFFFFu : 0x80000000u);
}

// ---------------------------------------------------------------------------
// K0 wprep: Wt_hi/Wt_lo[c][k] = split-cast transposed W (64 blocks).
// ---------------------------------------------------------------------------
__global__ __launch_bounds__(256) void wprep_kernel(const float* __restrict__ W,
                                                    ushort* __restrict__ Wt_hi,
                                                    ushort* __restrict__ Wt_lo) {
    const int t = threadIdx.x, blk = blockIdx.x;
    ushort his[4], los[4];
    #pragma unroll
    for (int kk = 0; kk < 4; kk++) {
        float v = W[(blk * 4 + kk) * 256 + t];
        ushort hi = f32_to_bf16_rne(v);
        his[kk] = hi;
        los[kk] = f32_to_bf16_rne(v - bf16_hi_to_f32(hi));
    }
    *(uint2*)&Wt_hi[(size_t)t * 256 + blk * 4] =
        make_uint2(((uint)his[0]) | (((uint)his[1]) << 16), ((uint)his[2]) | (((uint)his[3]) << 16));
    *(uint2*)&Wt_lo[(size_t)t * 256 + blk * 4] =
        make_uint2(((uint)los[0]) | (((uint)los[1]) << 16), ((uint)los[2]) | (((uint)los[3]) << 16));
}

// ---------------------------------------------------------------------------
// K1 gemm_fused (verbatim from R11, passing): barrier-free split-bf16 MFMA;
// writes f32 Wh[m][c] + log2-domain scores eL/rL.
// ---------------------------------------------------------------------------
#define BP 264   // B LDS pitch (ushorts)

__global__ __launch_bounds__(256, 2) void gemm_fused(const float* __restrict__ h,
                                                     const ushort* __restrict__ Wt_hi,
                                                     const ushort* __restrict__ Wt_lo,
                                                     const float* __restrict__ a_src,
                                                     const float* __restrict__ a_dst,
                                                     float* __restrict__ Wh,
                                                     float* __restrict__ eL,
                                                     float* __restrict__ rL) {
    __shared__ ushort Bs_h[64 * BP], Bs_l[64 * BP];

    const int t = threadIdx.x;
    const int m0 = blockIdx.x * 128;
    const int nb = blockIdx.y;                 // head
    const int b  = m0 >> 11;
    const int wid = t >> 6, lane = t & 63;
    const int c16 = lane & 15, quad = lane >> 4;

    {
        const int c = t >> 2, kq = t & 3;
        const ushort* sh = Wt_hi + (size_t)(nb * 64 + c) * 256 + kq * 64;
        const ushort* sl = Wt_lo + (size_t)(nb * 64 + c) * 256 + kq * 64;
        ushort* dh = &Bs_h[c * BP + kq * 64];
        ushort* dl = &Bs_l[c * BP + kq * 64];
        #pragma unroll
        for (int q = 0; q < 8; q++) {
            *(uint4*)(dh + q * 8) = *(const uint4*)(sh + q * 8);
            *(uint4*)(dl + q * 8) = *(const uint4*)(sl + q * 8);
        }
    }

    const int row0 = m0 + wid * 32 + c16;
    const float* hp0 = h + (size_t)row0 * 256 + quad * 8;
    const float* hp1 = hp0 + 16 * 256;

    float4 p0a = *(const float4*)hp0, p0b = *(const float4*)(hp0 + 4);
    float4 p1a = *(const float4*)hp1, p1b = *(const float4*)(hp1 + 4);

    __syncthreads();

    f32x4 acc[2][4] = {};
    for (int k0 = 0; k0 < 256; k0 += 32) {
        float v0[8] = {p0a.x, p0a.y, p0a.z, p0a.w, p0b.x, p0b.y, p0b.z, p0b.w};
        float v1[8] = {p1a.x, p1a.y, p1a.z, p1a.w, p1b.x, p1b.y, p1b.z, p1b.w};
        if (k0 < 224) {
            p0a = *(const float4*)(hp0 + k0 + 32); p0b = *(const float4*)(hp0 + k0 + 36);
            p1a = *(const float4*)(hp1 + k0 + 32); p1b = *(const float4*)(hp1 + k0 + 36);
        }
        bf16x8 ah0, al0, ah1, al1;
        split8(v0, &ah0, &al0);
        split8(v1, &ah1, &al1);
        #pragma unroll
        for (int fc = 0; fc < 4; fc++) {
            bf16x8 bhf = *(const bf16x8*)&Bs_h[(fc * 16 + c16) * BP + k0 + quad * 8];
            bf16x8 blf = *(const bf16x8*)&Bs_l[(fc * 16 + c16) * BP + k0 + quad * 8];
            acc[0][fc] = __builtin_amdgcn_mfma_f32_16x16x32_bf16(ah0, bhf, acc[0][fc], 0, 0, 0);
            acc[0][fc] = __builtin_amdgcn_mfma_f32_16x16x32_bf16(al0, bhf, acc[0][fc], 0, 0, 0);
            acc[0][fc] = __builtin_amdgcn_mfma_f32_16x16x32_bf16(ah0, blf, acc[0][fc], 0, 0, 0);
            acc[1][fc] = __builtin_amdgcn_mfma_f32_16x16x32_bf16(ah1, bhf, acc[1][fc], 0, 0, 0);
            acc[1][fc] = __builtin_amdgcn_mfma_f32_16x16x32_bf16(al1, bhf, acc[1][fc], 0, 0, 0);
            acc[1][fc] = __builtin_amdgcn_mfma_f32_16x16x32_bf16(ah1, blf, acc[1][fc], 0, 0, 0);
        }
    }

    {
        float avs[4], avd[4];
        #pragma unroll
        for (int fc = 0; fc < 4; fc++) {
            avs[fc] = a_src[nb * 64 + fc * 16 + c16];
            avd[fc] = a_dst[nb * 64 + fc * 16 + c16];
        }
        float ds[2][4] = {}, dd[2][4] = {};
        #pragma unroll
        for (int rw = 0; rw < 2; rw++)
            #pragma unroll
            for (int r = 0; r < 4; r++)
                #pragma unroll
                for (int fc = 0; fc < 4; fc++) {
                    ds[rw][r] += acc[rw][fc][r] * avs[fc];
                    dd[rw][r] += acc[rw][fc][r] * avd[fc];
                }
        #pragma unroll
        for (int off = 1; off < 16; off <<= 1)
            #pragma unroll
            for (int rw = 0; rw < 2; rw++)
                #pragma unroll
                for (int r = 0; r < 4; r++) {
                    ds[rw][r] += __shfl_xor(ds[rw][r], off);
                    dd[rw][r] += __shfl_xor(dd[rw][r], off);
                }
        if (c16 == 0) {
            #pragma unroll
            for (int rw = 0; rw < 2; rw++)
                #pragma unroll
                for (int r = 0; r < 4; r++) {
                    int m = m0 + wid * 32 + rw * 16 + quad * 4 + r;
                    int idx = (b * 4 + nb) * N_ + (m & 2047);
                    eL[idx] = ds[rw][r] * LOG2E;
                    rL[idx] = dd[rw][r] * LOG2E;
                }
        }
    }

    #pragma unroll
    for (int rw = 0; rw < 2; rw++)
        #pragma unroll
        for (int r = 0; r < 4; r++) {
            int n = m0 + wid * 32 + rw * 16 + quad * 4 + r;
            float* dst = Wh + (size_t)n * 256 + nb * 64;
            #pragma unroll
            for (int fc = 0; fc < 4; fc++)
                dst[fc * 16 + c16] = acc[rw][fc][r];
        }
}

// ---------------------------------------------------------------------------
// K2 rank (replaces 83-us bitonic sort): rank_j = #{k : key_k < key_j} with
// tie-free 64-bit keys (fenc(r)<<11 | j). Each thread counts its j against
// all 2048 LDS keys (broadcast reads, no divergence, no inner barriers),
// then scatters r_srt/perm/E_srt/F_srt. Grid (32 bh, 8) x 256 thr.
// ---------------------------------------------------------------------------
__global__ __launch_bounds__(256) void rank_kernel(const float* __restrict__ rL,
                                                   float* __restrict__ r_srt,
                                                   int* __restrict__ perm,
                                                   float* __restrict__ E_srt,
                                                   float* __restrict__ F_srt) {
    __shared__ unsigned long long keys[2048];
    const int bh = blockIdx.x, t = threadIdx.x;
    const int j = blockIdx.y * 256 + t;
    for (int s = t; s < 2048; s += 256)
        keys[s] = (((unsigned long long)fenc(rL[bh * 2048 + s])) << 11) | (unsigned)s;
    __syncthreads();
    const unsigned long long kj = keys[j];
    int rank = 0;
    for (int k0 = 0; k0 < 2048; k0 += 4) {
        unsigned long long k0v = keys[k0];
        unsigned long long k1v = keys[k0 + 1];
        unsigned long long k2v = keys[k0 + 2];
        unsigned long long k3v = keys[k0 + 3];
        rank += (int)(k0v < kj) + (int)(k1v < kj) + (int)(k2v < kj) + (int)(k3v < kj);
    }
    float rv = rL[bh * 2048 + j];
    r_srt[bh * 2048 + rank] = rv;
    perm[bh * 2048 + rank]  = j;
    E_srt[bh * 2048 + rank] = __builtin_amdgcn_exp2f(rv);
    F_srt[bh * 2048 + rank] = __builtin_amdgcn_exp2f(NEG * rv);
}

// ---------------------------------------------------------------------------
// K3 chunk sums (verbatim R11): per (bh, 32-j chunk) vector sums.
// ---------------------------------------------------------------------------
__global__ __launch_bounds__(256) void chunksum_kernel(const float* __restrict__ Wh,
                                                       const int* __restrict__ perm,
                                                       const float* __restrict__ E_srt,
                                                       const float* __restrict__ F_srt,
                                                       float* __restrict__ chunkF,
                                                       float* __restrict__ chunkE,
                                                       float* __restrict__ chunk_sf,
                                                       float* __restrict__ chunk_se) {
    const int bh = blockIdx.x;
    const int b = bh >> 2, hh = bh & 3;
    const int w = threadIdx.x >> 6, lane = threadIdx.x & 63;
    const int ch = blockIdx.y * 4 + w;
    const int j0 = ch * 32;

    float fv = 0.f, ev = 0.f; int pv = 0;
    if (lane < 32) {
        fv = F_srt[bh * 2048 + j0 + lane];
        ev = E_srt[bh * 2048 + j0 + lane];
        pv = perm[bh * 2048 + j0 + lane];
    }
    float v[32];
    #pragma unroll
    for (int jj = 0; jj < 32; jj++) {
        int pj = __shfl(pv, jj);
        v[jj] = Wh[((size_t)(b * 2048 + pj)) * 256 + hh * 64 + lane];
    }
    float aF = 0.f, aE = 0.f, sf = 0.f, se = 0.f;
    #pragma unroll
    for (int jj = 0; jj < 32; jj++) {
        float fj = __shfl(fv, jj), ej = __shfl(ev, jj);
        aF += fj * v[jj]; aE += ej * v[jj];
        sf += fj; se += ej;
    }
    size_t o = ((size_t)bh * 64 + ch) * 64 + lane;
    chunkF[o] = aF; chunkE[o] = aE;
    if (lane == 0) { chunk_sf[bh * 64 + ch] = sf; chunk_se[bh * 64 + ch] = se; }
}

// ---------------------------------------------------------------------------
// K4 scan (de-serialized): batch-load all 64 chunk values into registers
// (independent loads -> one latency), accumulate in-register; scalar chunk
// sums via wave shfl-scan (64 thr = 1 wave).
// ---------------------------------------------------------------------------
__global__ __launch_bounds__(64) void scan_kernel(const float* __restrict__ chunkF,
                                                  const float* __restrict__ chunkE,
                                                  const float* __restrict__ chunk_sf,
                                                  const float* __restrict__ chunk_se,
                                                  float* __restrict__ offF,
                                                  float* __restrict__ offE,
                                                  float* __restrict__ offF_s,
                                                  float* __restrict__ offE_s,
                                                  float* __restrict__ PF,
                                                  float* __restrict__ SES,
                                                  float* __restrict__ pf_s,
                                                  float* __restrict__ ses_s) {
    const int bh = blockIdx.x, d = threadIdx.x;   // 64 threads = 1 wave
    // ---- F: exclusive prefix over chunks ----
    {
        float cF[64];
        #pragma unroll
        for (int c = 0; c < 64; c++) cF[c] = chunkF[((size_t)bh * 64 + c) * 64 + d];
        float acc = 0.f;
        #pragma unroll
        for (int c = 0; c < 64; c++) {
            offF[((size_t)bh * 64 + c) * 64 + d] = acc;
            acc += cF[c];
        }
        PF[((size_t)bh * 2049 + 2048) * 64 + d] = acc;
    }
    // ---- E: exclusive suffix over chunks ----
    {
        float cE[64];
        #pragma unroll
        for (int c = 0; c < 64; c++) cE[c] = chunkE[((size_t)bh * 64 + c) * 64 + d];
        float acc = 0.f;
        #pragma unroll
        for (int c = 63; c >= 0; c--) {
            offE[((size_t)bh * 64 + c) * 64 + d] = acc;
            acc += cE[c];
        }
        SES[((size_t)bh * 2049 + 2048) * 64 + d] = 0.0f;
    }
    // ---- scalar sums via wave scans (thread d <-> chunk d) ----
    {
        float v = chunk_sf[bh * 64 + d];
        float s = v;
        #pragma unroll
        for (int off = 1; off < 64; off <<= 1) {
            float tv = __shfl_up(s, off);
            if (d >= off) s += tv;
        }
        offF_s[bh * 64 + d] = s - v;            // exclusive prefix
        if (d == 63) pf_s[bh * 2049 + 2048] = s; // total
    }
    {
        float v = chunk_se[bh * 64 + d];
        float s = v;
        #pragma unroll
        for (int off = 1; off < 64; off <<= 1) {
            float tv = __shfl_down(s, off);
            if (d < 64 - off) s += tv;
        }
        offE_s[bh * 64 + d] = s - v;            // exclusive suffix
        if (d == 0) ses_s[bh * 2049 + 2048] = 0.0f;
    }
}

// ---------------------------------------------------------------------------
// K5 emit (verbatim R11): full PF/SES rows + scalar dens.
// ---------------------------------------------------------------------------
__global__ __launch_bounds__(64) void emit_kernel(const float* __restrict__ Wh,
                                                  const int* __restrict__ perm,
                                                  const float* __restrict__ E_srt,
                                                  const float* __restrict__ F_srt,
                                                  const float* __restrict__ offF,
                                                  const float* __restrict__ offE,
                                                  const float* __restrict__ offF_s,
                                                  const float* __restrict__ offE_s,
                                                  float* __restrict__ PF,
                                                  float* __restrict__ SES,
                                                  float* __restrict__ pf_s,
                                                  float* __restrict__ ses_s) {
    const int bh = blockIdx.x, ch = blockIdx.y;
    const int b = bh >> 2, hh = bh & 3;
    const int d = threadIdx.x;
    const int j0 = ch * 32;

    float fv = 0.f, ev = 0.f; int pv = 0;
    if (d < 32) {
        fv = F_srt[bh * 2048 + j0 + d];
        ev = E_srt[bh * 2048 + j0 + d];
        pv = perm[bh * 2048 + j0 + d];
    }
    float v[32];
    #pragma unroll
    for (int jj = 0; jj < 32; jj++) {
        int pj = __shfl(pv, jj);
        v[jj] = Wh[((size_t)(b * 2048 + pj)) * 256 + hh * 64 + d];
    }
    float accF = offF[((size_t)bh * 64 + ch) * 64 + d];
    float sF   = offF_s[bh * 64 + ch];
    #pragma unroll
    for (int jj = 0; jj < 32; jj++) {
        float fj = __shfl(fv, jj);
        size_t ro = ((size_t)bh * 2049 + j0 + jj) * 64 + d;
        PF[ro] = accF;
        if (d == 0) pf_s[bh * 2049 + j0 + jj] = sF;
        accF += fj * v[jj];
        sF += fj;
    }
    float accE = offE[((size_t)bh * 64 + ch) * 64 + d];
    float sE   = offE_s[bh * 64 + ch];
    #pragma unroll
    for (int jj = 31; jj >= 0; jj--) {
        float ej = __shfl(ev, jj);
        accE += ej * v[jj];
        sE += ej;
        size_t ro = ((size_t)bh * 2049 + j0 + jj) * 64 + d;
        SES[ro] = accE;
        if (d == 0) ses_s[bh * 2049 + j0 + jj] = sE;
    }
}

// ---------------------------------------------------------------------------
// K6 final (verbatim R11): binary search t_i, gather PF/SES rows, normalize.
// ---------------------------------------------------------------------------
__global__ __launch_bounds__(256) void final_kernel(const float* __restrict__ eL,
                                                    const float* __restrict__ r_srt,
                                                    const float* __restrict__ PF,
                                                    const float* __restrict__ SES,
                                                    const float* __restrict__ pf_s,
                                                    const float* __restrict__ ses_s,
                                                    const float* __restrict__ bias,
                                                    float* __restrict__ out) {
    __shared__ float r_sh[2048];
    __shared__ int   t_sh[64];
    __shared__ float g_sh[64];
    const int bh = blockIdx.x, ig = blockIdx.y;
    const int b = bh >> 2, hh = bh & 3;
    const int t = threadIdx.x;

    for (int s = t; s < 2048; s += 256) r_sh[s] = r_srt[bh * 2048 + s];
    __syncthreads();
    if (t < 64) {
        int i = ig * 64 + t;
        float e = eL[bh * 2048 + i];
        float target = -e;
        int lo = 0, hi = 2048;
        while (lo < hi) {
            int mid = (lo + hi) >> 1;
            if (r_sh[mid] < target) lo = mid + 1; else hi = mid;
        }
        t_sh[t] = lo;
        g_sh[t] = __builtin_amdgcn_exp2f(-0.8f * e);
    }
    __syncthreads();

    const int w = t >> 6, lane = t & 63;
    const float bl = bias[hh * 64 + lane];
    #pragma unroll 4
    for (int q = 0; q < 16; q++) {
        int il = w * 16 + q;
        int ti = t_sh[il];
        float G = g_sh[il];
        size_t base = ((size_t)bh * 2049 + ti) * 64 + lane;
        float pf  = PF[base];
        float ses = SES[base];
        float dpf  = pf_s[bh * 2049 + ti];
        float dses = ses_s[bh * 2049 + ti];
        float num = G * pf + ses;
        float den = G * dpf + dses;
        int i = ig * 64 + il;
        out[((size_t)(b * 2048 + i)) * 256 + hh * 64 + lane] = num / den + bl;
    }
}

// ---------------------------------------------------------------------------
extern "C" void kernel_launch(void* const* d_in, const int* in_sizes, int n_in,
                              void* d_out, int out_size, void* d_ws, size_t ws_size,
                              hipStream_t stream) {
    const float* h     = (const float*)d_in[0];
    const float* W     = (const float*)d_in[1];
    const float* a_src = (const float*)d_in[2];
    const float* a_dst = (const float*)d_in[3];
    const float* bias  = (const float*)d_in[4];
    float* out = (float*)d_out;

    float* Wh       = (float*)d_ws;                  // 4,194,304
    float* eL       = Wh + (size_t)M_ * C_;          // 65536
    float* rL       = eL + 32 * N_;
    float* r_srt    = rL + 32 * N_;
    float* E_srt    = r_srt + 32 * N_;
    float* F_srt    = E_srt + 32 * N_;
    float* chunkF   = F_srt + 32 * N_;               // 32*64*64
    float* chunkE   = chunkF + 32 * 64 * 64;
    float* chunk_sf = chunkE + 32 * 64 * 64;         // 2048
    float* chunk_se = chunk_sf + 32 * 64;
    float* offF     = chunk_se + 32 * 64;            // 32*64*64
    float* offE     = offF + 32 * 64 * 64;
    float* offF_s   = offE + 32 * 64 * 64;           // 2048
    float* offE_s   = offF_s + 32 * 64;
    float* PF       = offE_s + 32 * 64;              // 32*2049*64
    float* SES      = PF + (size_t)32 * 2049 * 64;
    float* pf_s     = SES + (size_t)32 * 2049 * 64;  // 32*2049
    float* ses_s    = pf_s + 32 * 2049;
    int*   perm     = (int*)(ses_s + 32 * 2049);     // 65536 ints
    ushort* Wt_hi   = (ushort*)(perm + 32 * N_);     // 65536 ushorts
    ushort* Wt_lo   = Wt_hi + 256 * 256;

    wprep_kernel<<<64, 256, 0, stream>>>(W, Wt_hi, Wt_lo);
    gemm_fused<<<dim3(M_ / 128, 4), 256, 0, stream>>>(h, Wt_hi, Wt_lo, a_src, a_dst,
                                                      Wh, eL, rL);
    rank_kernel<<<dim3(32, 8), 256, 0, stream>>>(rL, r_srt, perm, E_srt, F_srt);
    chunksum_kernel<<<dim3(32, 16), 256, 0, stream>>>(Wh, perm, E_srt, F_srt,
                                                      chunkF, chunkE, chunk_sf, chunk_se);
    scan_kernel<<<32, 64, 0, stream>>>(chunkF, chunkE, chunk_sf, chunk_se,
                                       offF, offE, offF_s, offE_s,
                                       PF, SES, pf_s, ses_s);
    emit_kernel<<<dim3(32, 64), 64, 0, stream>>>(Wh, perm, E_srt, F_srt,
                                                 offF, offE, offF_s, offE_s,
                                                 PF, SES, pf_s, ses_s);
    final_kernel<<<dim3(32, 32), 256, 0, stream>>>(eL, r_srt, PF, SES, pf_s, ses_s,
                                                   bias, out);
}

// Round 13
// 125.303 us; speedup vs baseline: 1.8378x; 1.1464x over previous
//
#include <hip/hip_runtime.h>
#include <math.h>

#define B_   8
#define N_   2048
#define IN_  256
#define H_   4
#define D_   64
#define C_   256            // H_*D_
#define M_   (B_*N_)        // 16384
#define NEG  0.2f
#define LOG2E 1.4426950408889634f

typedef short bf16x8 __attribute__((ext_vector_type(8)));
typedef float f32x4  __attribute__((ext_vector_type(4)));
typedef float f32x2  __attribute__((ext_vector_type(2)));

__device__ inline ushort f32_to_bf16_rne(float x) {
    union { float f; unsigned u; } c; c.f = x;
    unsigned u = c.u + 0x7FFFu + ((c.u >> 16) & 1u);
    return (ushort)(u >> 16);
}
__device__ inline float bf16_hi_to_f32(ushort u) {
    union { unsigned u; float f; } c; c.u = ((unsigned)u) << 16;
    return c.f;
}
// packed split: hi = rne(v) (exact), lo = trunc(v - hi) (err ~2^-18 of v).
// Per element ~5 VALU vs ~8 for the naive version.
__device__ inline void split8p(const float v[8], bf16x8* hi, bf16x8* lo) {
    union { bf16x8 v; uint u[4]; } H, L;
    #pragma unroll
    for (int p = 0; p < 4; p++) {
        uint u0 = __float_as_uint(v[2 * p]);
        uint u1 = __float_as_uint(v[2 * p + 1]);
        uint r0 = u0 + 0x7FFFu + ((u0 >> 16) & 1u);
        uint r1 = u1 + 0x7FFFu + ((u1 >> 16) & 1u);
        H.u[p] = __builtin_amdgcn_perm(r1, r0, 0x07060302u);
        float l0 = v[2 * p]     - __uint_as_float(r0 & 0xFFFF0000u);
        float l1 = v[2 * p + 1] - __uint_as_float(r1 & 0xFFFF0000u);
        L.u[p] = __builtin_amdgcn_perm(__float_as_uint(l1), __float_as_uint(l0), 0x07060302u);
    }
    *hi = H.v; *lo = L.v;
}

// ---------------------------------------------------------------------------
// Kernel 0: wprep (64 blocks): Wt_hi/Wt_lo[c][k] = split-cast transposed W.
// ---------------------------------------------------------------------------
__global__ __launch_bounds__(256) void wprep_kernel(const float* __restrict__ W,
                                                    ushort* __restrict__ Wt_hi,
                                                    ushort* __restrict__ Wt_lo) {
    const int t = threadIdx.x, blk = blockIdx.x;
    ushort his[4], los[4];
    #pragma unroll
    for (int kk = 0; kk < 4; kk++) {
        float v = W[(blk * 4 + kk) * 256 + t];
        ushort hi = f32_to_bf16_rne(v);
        his[kk] = hi;
        los[kk] = f32_to_bf16_rne(v - bf16_hi_to_f32(hi));
    }
    *(uint2*)&Wt_hi[(size_t)t * 256 + blk * 4] =
        make_uint2(((uint)his[0]) | (((uint)his[1]) << 16), ((uint)his[2]) | (((uint)his[3]) << 16));
    *(uint2*)&Wt_lo[(size_t)t * 256 + blk * 4] =
        make_uint2(((uint)los[0]) | (((uint)los[1]) << 16), ((uint)los[2]) | (((uint)los[3]) << 16));
}

// ---------------------------------------------------------------------------
// Kernel 1: fused GEMM (barrier-free K-loop) + in-register cast + scores.
// R10 structure; changes: depth-2 A prefetch (2 k-slice register slots) and
// the cheaper split8p. Grid (128, 4) = 512 blocks x 256 thr, 128m x 64c.
// ---------------------------------------------------------------------------
#define BP 264   // B LDS pitch (ushorts)

__global__ __launch_bounds__(256, 2) void gemm_fused(const float* __restrict__ h,
                                                     const ushort* __restrict__ Wt_hi,
                                                     const ushort* __restrict__ Wt_lo,
                                                     const float* __restrict__ a_src,
                                                     const float* __restrict__ a_dst,
                                                     ushort* __restrict__ Wht,
                                                     float* __restrict__ Ee,
                                                     float* __restrict__ Ff,
                                                     float* __restrict__ Gg) {
    __shared__ ushort Bs_h[64 * BP], Bs_l[64 * BP];

    const int t = threadIdx.x;
    const int m0 = blockIdx.x * 128;
    const int nb = blockIdx.y;                 // head
    const int b  = m0 >> 11;
    const int wid = t >> 6, lane = t & 63;
    const int c16 = lane & 15, quad = lane >> 4;

    // ---- stage B once ----
    {
        const int c = t >> 2, kq = t & 3;
        const ushort* sh = Wt_hi + (size_t)(nb * 64 + c) * 256 + kq * 64;
        const ushort* sl = Wt_lo + (size_t)(nb * 64 + c) * 256 + kq * 64;
        ushort* dh = &Bs_h[c * BP + kq * 64];
        ushort* dl = &Bs_l[c * BP + kq * 64];
        #pragma unroll
        for (int q = 0; q < 8; q++) {
            *(uint4*)(dh + q * 8) = *(const uint4*)(sh + q * 8);
            *(uint4*)(dl + q * 8) = *(const uint4*)(sl + q * 8);
        }
    }

    const int row0 = m0 + wid * 32 + c16;
    const float* hp0 = h + (size_t)row0 * 256 + quad * 8;
    const float* hp1 = hp0 + 16 * 256;

    // depth-2 A prefetch: slots for k0 and k0+32
    float4 pa[2][4];
    #pragma unroll
    for (int s = 0; s < 2; s++) {
        pa[s][0] = *(const float4*)(hp0 + s * 32);
        pa[s][1] = *(const float4*)(hp0 + s * 32 + 4);
        pa[s][2] = *(const float4*)(hp1 + s * 32);
        pa[s][3] = *(const float4*)(hp1 + s * 32 + 4);
    }

    __syncthreads();                            // B staged

    f32x4 acc[2][4] = {};
    for (int k0 = 0; k0 < 256; k0 += 32) {
        const int s = (k0 >> 5) & 1;
        float v0[8] = {pa[s][0].x, pa[s][0].y, pa[s][0].z, pa[s][0].w,
                       pa[s][1].x, pa[s][1].y, pa[s][1].z, pa[s][1].w};
        float v1[8] = {pa[s][2].x, pa[s][2].y, pa[s][2].z, pa[s][2].w,
                       pa[s][3].x, pa[s][3].y, pa[s][3].z, pa[s][3].w};
        if (k0 < 192) {                         // refill slot s with k0+64
            pa[s][0] = *(const float4*)(hp0 + k0 + 64);
            pa[s][1] = *(const float4*)(hp0 + k0 + 68);
            pa[s][2] = *(const float4*)(hp1 + k0 + 64);
            pa[s][3] = *(const float4*)(hp1 + k0 + 68);
        }
        bf16x8 ah0, al0, ah1, al1;
        split8p(v0, &ah0, &al0);
        split8p(v1, &ah1, &al1);
        #pragma unroll
        for (int fc = 0; fc < 4; fc++) {
            bf16x8 bhf = *(const bf16x8*)&Bs_h[(fc * 16 + c16) * BP + k0 + quad * 8];
            bf16x8 blf = *(const bf16x8*)&Bs_l[(fc * 16 + c16) * BP + k0 + quad * 8];
            acc[0][fc] = __builtin_amdgcn_mfma_f32_16x16x32_bf16(ah0, bhf, acc[0][fc], 0, 0, 0);
            acc[0][fc] = __builtin_amdgcn_mfma_f32_16x16x32_bf16(al0, bhf, acc[0][fc], 0, 0, 0);
            acc[0][fc] = __builtin_amdgcn_mfma_f32_16x16x32_bf16(ah0, blf, acc[0][fc], 0, 0, 0);
            acc[1][fc] = __builtin_amdgcn_mfma_f32_16x16x32_bf16(ah1, bhf, acc[1][fc], 0, 0, 0);
            acc[1][fc] = __builtin_amdgcn_mfma_f32_16x16x32_bf16(al1, bhf, acc[1][fc], 0, 0, 0);
            acc[1][fc] = __builtin_amdgcn_mfma_f32_16x16x32_bf16(ah1, blf, acc[1][fc], 0, 0, 0);
        }
    }

    // ---- scores epilogue: el/er from acc (exact f32), butterfly over c16 ----
    {
        float avs[4], avd[4];
        #pragma unroll
        for (int fc = 0; fc < 4; fc++) {
            avs[fc] = a_src[nb * 64 + fc * 16 + c16];
            avd[fc] = a_dst[nb * 64 + fc * 16 + c16];
        }
        float ds[2][4] = {}, dd[2][4] = {};
        #pragma unroll
        for (int rw = 0; rw < 2; rw++)
            #pragma unroll
            for (int r = 0; r < 4; r++)
                #pragma unroll
                for (int fc = 0; fc < 4; fc++) {
                    ds[rw][r] += acc[rw][fc][r] * avs[fc];
                    dd[rw][r] += acc[rw][fc][r] * avd[fc];
                }
        #pragma unroll
        for (int off = 1; off < 16; off <<= 1)
            #pragma unroll
            for (int rw = 0; rw < 2; rw++)
                #pragma unroll
                for (int r = 0; r < 4; r++) {
                    ds[rw][r] += __shfl_xor(ds[rw][r], off);
                    dd[rw][r] += __shfl_xor(dd[rw][r], off);
                }
        if (c16 == 0) {
            #pragma unroll
            for (int rw = 0; rw < 2; rw++)
                #pragma unroll
                for (int r = 0; r < 4; r++) {
                    int m = m0 + wid * 32 + rw * 16 + quad * 4 + r;
                    int idx = (b * 4 + nb) * N_ + (m & 2047);
                    float ee = ds[rw][r] * LOG2E;   // el (log2-domain)
                    float rr = dd[rw][r] * LOG2E;   // er (log2-domain)
                    Ee[idx] = __builtin_amdgcn_exp2f(rr);
                    Ff[idx] = __builtin_amdgcn_exp2f(NEG * rr);
                    Gg[idx] = __builtin_amdgcn_exp2f(-0.8f * ee);
                }
        }
    }

    // ---- Wht epilogue: transpose via LDS (reuse Bs_h), 256-B stores ----
    __syncthreads();
    ushort* Es = Bs_h;
    #pragma unroll
    for (int rw = 0; rw < 2; rw++) {
        const int nloc = wid * 32 + rw * 16 + quad * 4;
        #pragma unroll
        for (int fc = 0; fc < 4; fc++) {
            const int d = fc * 16 + c16;
            uint2 pk = make_uint2(
                ((uint)f32_to_bf16_rne(acc[rw][fc][0])) | (((uint)f32_to_bf16_rne(acc[rw][fc][1])) << 16),
                ((uint)f32_to_bf16_rne(acc[rw][fc][2])) | (((uint)f32_to_bf16_rne(acc[rw][fc][3])) << 16));
            *(uint2*)&Es[d * 136 + nloc] = pk;
        }
    }
    __syncthreads();
    {
        const int d = t >> 2, ch = t & 3;
        ushort* dst = Wht + ((size_t)(b * 4 + nb) * 64 + d) * N_ + (m0 & 2047) + ch * 32;
        const ushort* srcl = &Es[d * 136 + ch * 32];
        #pragma unroll
        for (int q = 0; q < 4; q++)
            *(uint4*)(dst + q * 8) = *(const uint4*)(srcl + q * 8);
    }
}

// ---------------------------------------------------------------------------
// Kernel 2: attention (R10 structure). q_ij = max(E_j, G_i*F_j), processed as
// float2 pairs (v_pk_mul/v_pk_max) + RNE bf16 pack. Grid (bh=32, itile=16),
// 256 thr = 4 waves x 32 i (g=2). Double-buffered LDS, 1 barrier/tile.
// ---------------------------------------------------------------------------
#define TPA 80   // pitch (ushorts) = 160 B (measured conflict-free)

__global__ __launch_bounds__(256, 2) void attn_kernel(const ushort* __restrict__ Wht,
                                                      const float* __restrict__ Ee,
                                                      const float* __restrict__ Ff,
                                                      const float* __restrict__ Gg,
                                                      const float* __restrict__ bias,
                                                      float* __restrict__ out) {
    __shared__ ushort Whs[2][64 * TPA];
    __shared__ float E_s[2][64], F_s[2][64];
    const int t = threadIdx.x;
    const int bh = blockIdx.x, b = bh >> 2, hh = bh & 3;
    const int wid = t >> 6, lane = t & 63;
    const int c16 = lane & 15, quad = lane >> 4;
    const int ibase = blockIdx.y * 128 + wid * 32;
    const int sd = t >> 3, sch = t & 7;

    f32x2 Gi2[2];
    #pragma unroll
    for (int g = 0; g < 2; g++) {
        float gv = Gg[bh * N_ + ibase + g * 16 + c16];
        Gi2[g].x = gv; Gi2[g].y = gv;
    }

    f32x4 acc[2][4] = {};
    f32x4 den[2] = {};
    const bf16x8 ones = {0x3F80, 0x3F80, 0x3F80, 0x3F80,
                         0x3F80, 0x3F80, 0x3F80, 0x3F80};
    const ushort* WhtB = Wht + (size_t)bh * 64 * N_;
    const float* Eb = Ee + (size_t)bh * N_;
    const float* Fb = Ff + (size_t)bh * N_;

    uint4 w0 = *(const uint4*)(WhtB + (size_t)sd * N_ + sch * 8);
    uint4 w1 = *(const uint4*)(WhtB + (size_t)(sd + 32) * N_ + sch * 8);
    float ev_e = 0.f, ev_f = 0.f;
    if (t < 64) { ev_e = Eb[t]; ev_f = Fb[t]; }

    for (int jt = 0; jt < 32; jt++) {
        const int buf = jt & 1;
        *(uint4*)&Whs[buf][sd * TPA + sch * 8]        = w0;
        *(uint4*)&Whs[buf][(sd + 32) * TPA + sch * 8] = w1;
        if (t < 64) { E_s[buf][t] = ev_e; F_s[buf][t] = ev_f; }
        if (jt < 31) {
            const int j1 = (jt + 1) * 64;
            w0 = *(const uint4*)(WhtB + (size_t)sd * N_ + j1 + sch * 8);
            w1 = *(const uint4*)(WhtB + (size_t)(sd + 32) * N_ + j1 + sch * 8);
            if (t < 64) { ev_e = Eb[j1 + t]; ev_f = Fb[j1 + t]; }
        }
        __syncthreads();
        #pragma unroll
        for (int ks = 0; ks < 2; ks++) {
            const int jb = ks * 32 + quad * 8;
            f32x2 e2[4], f2[4];
            {
                float4 e0 = *(const float4*)&E_s[buf][jb];
                float4 e1 = *(const float4*)&E_s[buf][jb + 4];
                float4 f0 = *(const float4*)&F_s[buf][jb];
                float4 f1 = *(const float4*)&F_s[buf][jb + 4];
                e2[0].x = e0.x; e2[0].y = e0.y; e2[1].x = e0.z; e2[1].y = e0.w;
                e2[2].x = e1.x; e2[2].y = e1.y; e2[3].x = e1.z; e2[3].y = e1.w;
                f2[0].x = f0.x; f2[0].y = f0.y; f2[1].x = f0.z; f2[1].y = f0.w;
                f2[2].x = f1.x; f2[2].y = f1.y; f2[3].x = f1.z; f2[3].y = f1.w;
            }
            bf16x8 bfr[4];
            #pragma unroll
            for (int fd = 0; fd < 4; fd++)
                bfr[fd] = *(const bf16x8*)&Whs[buf][(fd * 16 + c16) * TPA + jb];
            #pragma unroll
            for (int g = 0; g < 2; g++) {
                union { bf16x8 v; uint u[4]; } af;
                #pragma unroll
                for (int jp = 0; jp < 4; jp++) {
                    f32x2 q2 = __builtin_elementwise_max(e2[jp], Gi2[g] * f2[jp]);
                    uint a = __float_as_uint(q2.x) + 0x8000u;
                    uint bq = __float_as_uint(q2.y) + 0x8000u;
                    af.u[jp] = __builtin_amdgcn_perm(bq, a, 0x07060302u);
                }
                #pragma unroll
                for (int fd = 0; fd < 4; fd++)
                    acc[g][fd] = __builtin_amdgcn_mfma_f32_16x16x32_bf16(af.v, bfr[fd], acc[g][fd], 0, 0, 0);
                den[g] = __builtin_amdgcn_mfma_f32_16x16x32_bf16(af.v, ones, den[g], 0, 0, 0);
            }
        }
    }

    float bl[4];
    #pragma unroll
    for (int fd = 0; fd < 4; fd++) bl[fd] = bias[hh * 64 + fd * 16 + c16];
    #pragma unroll
    for (int g = 0; g < 2; g++)
        #pragma unroll
        for (int r = 0; r < 4; r++) {
            int i = ibase + g * 16 + quad * 4 + r;
            float inv = 1.0f / den[g][r];
            float* dst = out + (size_t)(b * N_ + i) * C_ + hh * 64;
            #pragma unroll
            for (int fd = 0; fd < 4; fd++)
                dst[fd * 16 + c16] = acc[g][fd][r] * inv + bl[fd];
        }
}

// ---------------------------------------------------------------------------
extern "C" void kernel_launch(void* const* d_in, const int* in_sizes, int n_in,
                              void* d_out, int out_size, void* d_ws, size_t ws_size,
                              hipStream_t stream) {
    const float* h     = (const float*)d_in[0];
    const float* W     = (const float*)d_in[1];
    const float* a_src = (const float*)d_in[2];
    const float* a_dst = (const float*)d_in[3];
    const float* bias  = (const float*)d_in[4];
    float* out = (float*)d_out;

    ushort* Wt_hi = (ushort*)d_ws;                       // 256*256
    ushort* Wt_lo = Wt_hi + 256 * 256;
    ushort* Wht   = Wt_lo + 256 * 256;                   // M_*C_ bf16 [bh][d][n]
    float*  Ee    = (float*)(Wht + (size_t)M_ * C_);     // 32*2048
    float*  Ff    = Ee + 32 * N_;
    float*  Gg    = Ff + 32 * N_;

    wprep_kernel<<<64, 256, 0, stream>>>(W, Wt_hi, Wt_lo);
    gemm_fused<<<dim3(M_ / 128, 4), 256, 0, stream>>>(h, Wt_hi, Wt_lo, a_src, a_dst,
                                                      Wht, Ee, Ff, Gg);
    attn_kernel<<<dim3(32, 16), 256, 0, stream>>>(Wht, Ee, Ff, Gg, bias, out);
}

// Round 14
// 123.019 us; speedup vs baseline: 1.8719x; 1.0186x over previous
//
#include <hip/hip_runtime.h>
#include <math.h>

#define B_   8
#define N_   2048
#define IN_  256
#define H_   4
#define D_   64
#define C_   256            // H_*D_
#define M_   (B_*N_)        // 16384
#define NEG  0.2f
#define LOG2E 1.4426950408889634f

typedef short bf16x8 __attribute__((ext_vector_type(8)));
typedef float f32x4  __attribute__((ext_vector_type(4)));
typedef float f32x2  __attribute__((ext_vector_type(2)));

typedef __attribute__((address_space(3))) uint lds_u32;
typedef __attribute__((address_space(1))) uint glb_u32;

// async global -> LDS: wave-uniform LDS base, HW adds lane*size [m03/m97]
__device__ inline void glds16(const void* g, void* l) {
    __builtin_amdgcn_global_load_lds((const glb_u32*)g, (lds_u32*)l, 16, 0, 0);
}
__device__ inline void glds4(const void* g, void* l) {
    __builtin_amdgcn_global_load_lds((const glb_u32*)g, (lds_u32*)l, 4, 0, 0);
}

__device__ inline ushort f32_to_bf16_rne(float x) {
    union { float f; unsigned u; } c; c.f = x;
    unsigned u = c.u + 0x7FFFu + ((c.u >> 16) & 1u);
    return (ushort)(u >> 16);
}
__device__ inline float bf16_hi_to_f32(ushort u) {
    union { unsigned u; float f; } c; c.u = ((unsigned)u) << 16;
    return c.f;
}
// packed split: hi = rne(v) (exact), lo = trunc(v - hi) (err ~2^-18 of v)
__device__ inline void split8p(const float v[8], bf16x8* hi, bf16x8* lo) {
    union { bf16x8 v; uint u[4]; } H, L;
    #pragma unroll
    for (int p = 0; p < 4; p++) {
        uint u0 = __float_as_uint(v[2 * p]);
        uint u1 = __float_as_uint(v[2 * p + 1]);
        uint r0 = u0 + 0x7FFFu + ((u0 >> 16) & 1u);
        uint r1 = u1 + 0x7FFFu + ((u1 >> 16) & 1u);
        H.u[p] = __builtin_amdgcn_perm(r1, r0, 0x07060302u);
        float l0 = v[2 * p]     - __uint_as_float(r0 & 0xFFFF0000u);
        float l1 = v[2 * p + 1] - __uint_as_float(r1 & 0xFFFF0000u);
        L.u[p] = __builtin_amdgcn_perm(__float_as_uint(l1), __float_as_uint(l0), 0x07060302u);
    }
    *hi = H.v; *lo = L.v;
}

// ---------------------------------------------------------------------------
// Kernel 0: wprep (64 blocks): Wt_hi/Wt_lo[c][k] = split-cast transposed W.
// ---------------------------------------------------------------------------
__global__ __launch_bounds__(256) void wprep_kernel(const float* __restrict__ W,
                                                    ushort* __restrict__ Wt_hi,
                                                    ushort* __restrict__ Wt_lo) {
    const int t = threadIdx.x, blk = blockIdx.x;
    ushort his[4], los[4];
    #pragma unroll
    for (int kk = 0; kk < 4; kk++) {
        float v = W[(blk * 4 + kk) * 256 + t];
        ushort hi = f32_to_bf16_rne(v);
        his[kk] = hi;
        los[kk] = f32_to_bf16_rne(v - bf16_hi_to_f32(hi));
    }
    *(uint2*)&Wt_hi[(size_t)t * 256 + blk * 4] =
        make_uint2(((uint)his[0]) | (((uint)his[1]) << 16), ((uint)his[2]) | (((uint)his[3]) << 16));
    *(uint2*)&Wt_lo[(size_t)t * 256 + blk * 4] =
        make_uint2(((uint)los[0]) | (((uint)los[1]) << 16), ((uint)los[2]) | (((uint)los[3]) << 16));
}

// ---------------------------------------------------------------------------
// Kernel 1: fused GEMM (barrier-free K-loop) + in-register cast + scores.
// As R13; the Wht epilogue now writes TILE-MAJOR SWIZZLED layout:
//   Wht_t[bh][tile=n>>6][d][chunk ^ (d&7)]  (chunk = (n&63)>>3, 8 ushorts)
// so attn can stage tiles verbatim with global_load_lds and read B-frags
// conflict-free from the unpadded LDS image.
// ---------------------------------------------------------------------------
#define BP 264   // B LDS pitch (ushorts)

__global__ __launch_bounds__(256, 2) void gemm_fused(const float* __restrict__ h,
                                                     const ushort* __restrict__ Wt_hi,
                                                     const ushort* __restrict__ Wt_lo,
                                                     const float* __restrict__ a_src,
                                                     const float* __restrict__ a_dst,
                                                     ushort* __restrict__ Wht_t,
                                                     float* __restrict__ Ee,
                                                     float* __restrict__ Ff,
                                                     float* __restrict__ Gg) {
    __shared__ ushort Bs_h[64 * BP], Bs_l[64 * BP];

    const int t = threadIdx.x;
    const int m0 = blockIdx.x * 128;
    const int nb = blockIdx.y;                 // head
    const int b  = m0 >> 11;
    const int wid = t >> 6, lane = t & 63;
    const int c16 = lane & 15, quad = lane >> 4;

    // ---- stage B once ----
    {
        const int c = t >> 2, kq = t & 3;
        const ushort* sh = Wt_hi + (size_t)(nb * 64 + c) * 256 + kq * 64;
        const ushort* sl = Wt_lo + (size_t)(nb * 64 + c) * 256 + kq * 64;
        ushort* dh = &Bs_h[c * BP + kq * 64];
        ushort* dl = &Bs_l[c * BP + kq * 64];
        #pragma unroll
        for (int q = 0; q < 8; q++) {
            *(uint4*)(dh + q * 8) = *(const uint4*)(sh + q * 8);
            *(uint4*)(dl + q * 8) = *(const uint4*)(sl + q * 8);
        }
    }

    const int row0 = m0 + wid * 32 + c16;
    const float* hp0 = h + (size_t)row0 * 256 + quad * 8;
    const float* hp1 = hp0 + 16 * 256;

    // depth-2 A prefetch
    float4 pa[2][4];
    #pragma unroll
    for (int s = 0; s < 2; s++) {
        pa[s][0] = *(const float4*)(hp0 + s * 32);
        pa[s][1] = *(const float4*)(hp0 + s * 32 + 4);
        pa[s][2] = *(const float4*)(hp1 + s * 32);
        pa[s][3] = *(const float4*)(hp1 + s * 32 + 4);
    }

    __syncthreads();                            // B staged

    f32x4 acc[2][4] = {};
    for (int k0 = 0; k0 < 256; k0 += 32) {
        const int s = (k0 >> 5) & 1;
        float v0[8] = {pa[s][0].x, pa[s][0].y, pa[s][0].z, pa[s][0].w,
                       pa[s][1].x, pa[s][1].y, pa[s][1].z, pa[s][1].w};
        float v1[8] = {pa[s][2].x, pa[s][2].y, pa[s][2].z, pa[s][2].w,
                       pa[s][3].x, pa[s][3].y, pa[s][3].z, pa[s][3].w};
        if (k0 < 192) {
            pa[s][0] = *(const float4*)(hp0 + k0 + 64);
            pa[s][1] = *(const float4*)(hp0 + k0 + 68);
            pa[s][2] = *(const float4*)(hp1 + k0 + 64);
            pa[s][3] = *(const float4*)(hp1 + k0 + 68);
        }
        bf16x8 ah0, al0, ah1, al1;
        split8p(v0, &ah0, &al0);
        split8p(v1, &ah1, &al1);
        #pragma unroll
        for (int fc = 0; fc < 4; fc++) {
            bf16x8 bhf = *(const bf16x8*)&Bs_h[(fc * 16 + c16) * BP + k0 + quad * 8];
            bf16x8 blf = *(const bf16x8*)&Bs_l[(fc * 16 + c16) * BP + k0 + quad * 8];
            acc[0][fc] = __builtin_amdgcn_mfma_f32_16x16x32_bf16(ah0, bhf, acc[0][fc], 0, 0, 0);
            acc[0][fc] = __builtin_amdgcn_mfma_f32_16x16x32_bf16(al0, bhf, acc[0][fc], 0, 0, 0);
            acc[0][fc] = __builtin_amdgcn_mfma_f32_16x16x32_bf16(ah0, blf, acc[0][fc], 0, 0, 0);
            acc[1][fc] = __builtin_amdgcn_mfma_f32_16x16x32_bf16(ah1, bhf, acc[1][fc], 0, 0, 0);
            acc[1][fc] = __builtin_amdgcn_mfma_f32_16x16x32_bf16(al1, bhf, acc[1][fc], 0, 0, 0);
            acc[1][fc] = __builtin_amdgcn_mfma_f32_16x16x32_bf16(ah1, blf, acc[1][fc], 0, 0, 0);
        }
    }

    // ---- scores epilogue: el/er from acc (exact f32), butterfly over c16 ----
    {
        float avs[4], avd[4];
        #pragma unroll
        for (int fc = 0; fc < 4; fc++) {
            avs[fc] = a_src[nb * 64 + fc * 16 + c16];
            avd[fc] = a_dst[nb * 64 + fc * 16 + c16];
        }
        float ds[2][4] = {}, dd[2][4] = {};
        #pragma unroll
        for (int rw = 0; rw < 2; rw++)
            #pragma unroll
            for (int r = 0; r < 4; r++)
                #pragma unroll
                for (int fc = 0; fc < 4; fc++) {
                    ds[rw][r] += acc[rw][fc][r] * avs[fc];
                    dd[rw][r] += acc[rw][fc][r] * avd[fc];
                }
        #pragma unroll
        for (int off = 1; off < 16; off <<= 1)
            #pragma unroll
            for (int rw = 0; rw < 2; rw++)
                #pragma unroll
                for (int r = 0; r < 4; r++) {
                    ds[rw][r] += __shfl_xor(ds[rw][r], off);
                    dd[rw][r] += __shfl_xor(dd[rw][r], off);
                }
        if (c16 == 0) {
            #pragma unroll
            for (int rw = 0; rw < 2; rw++)
                #pragma unroll
                for (int r = 0; r < 4; r++) {
                    int m = m0 + wid * 32 + rw * 16 + quad * 4 + r;
                    int idx = (b * 4 + nb) * N_ + (m & 2047);
                    float ee = ds[rw][r] * LOG2E;
                    float rr = dd[rw][r] * LOG2E;
                    Ee[idx] = __builtin_amdgcn_exp2f(rr);
                    Ff[idx] = __builtin_amdgcn_exp2f(NEG * rr);
                    Gg[idx] = __builtin_amdgcn_exp2f(-0.8f * ee);
                }
        }
    }

    // ---- Wht epilogue: transpose via LDS (reuse Bs_h), write tile-major
    //      swizzled global image ----
    __syncthreads();
    ushort* Es = Bs_h;
    #pragma unroll
    for (int rw = 0; rw < 2; rw++) {
        const int nloc = wid * 32 + rw * 16 + quad * 4;
        #pragma unroll
        for (int fc = 0; fc < 4; fc++) {
            const int d = fc * 16 + c16;
            uint2 pk = make_uint2(
                ((uint)f32_to_bf16_rne(acc[rw][fc][0])) | (((uint)f32_to_bf16_rne(acc[rw][fc][1])) << 16),
                ((uint)f32_to_bf16_rne(acc[rw][fc][2])) | (((uint)f32_to_bf16_rne(acc[rw][fc][3])) << 16));
            *(uint2*)&Es[d * 136 + nloc] = pk;
        }
    }
    __syncthreads();
    {
        const int d = t >> 2, ch = t & 3;       // ch: 2 tiles x 2 halves
        const int tt0 = (m0 & 2047) >> 6;       // first j-tile index of this block
        const int lt = ch >> 1, half = ch & 1;
        ushort* dst = Wht_t + (((size_t)(b * 4 + nb) * 32 + tt0 + lt) * 64 + d) * 64;
        const ushort* srcl = &Es[d * 136 + ch * 32];
        #pragma unroll
        for (int q = 0; q < 4; q++) {
            int cj = half * 4 + q;
            *(uint4*)(dst + ((cj ^ (d & 7)) * 8)) = *(const uint4*)(srcl + q * 8);
        }
    }
}

// ---------------------------------------------------------------------------
// Kernel 2: attention. Staging via async global_load_lds (zero VALU/VGPR):
// Wht tiles are pre-swizzled in global, copied verbatim to unpadded LDS;
// B-frag reads apply chunk^(c16&7) -> 2 lanes/bank (free). Order per tile:
// barrier (drains prev issue) -> issue jt+1 glds -> consume jt, so loads get
// a full consume-phase to land. q_ij = max(E_j, G_i*F_j), packed f32x2.
// Grid (bh=32, itile=16), 256 thr = 4 waves x 32 i (g=2).
// ---------------------------------------------------------------------------
__global__ __launch_bounds__(256, 2) void attn_kernel(const ushort* __restrict__ Wht_t,
                                                      const float* __restrict__ Ee,
                                                      const float* __restrict__ Ff,
                                                      const float* __restrict__ Gg,
                                                      const float* __restrict__ bias,
                                                      float* __restrict__ out) {
    __shared__ ushort Whs[2][64 * 64];          // unpadded 8 KB tiles
    __shared__ float E_s[2][64], F_s[2][64];
    const int t = threadIdx.x;
    const int bh = blockIdx.x, b = bh >> 2, hh = bh & 3;
    const int wid = t >> 6, lane = t & 63;
    const int c16 = lane & 15, quad = lane >> 4;
    const int ibase = blockIdx.y * 128 + wid * 32;

    f32x2 Gi2[2];
    #pragma unroll
    for (int g = 0; g < 2; g++) {
        float gv = Gg[bh * N_ + ibase + g * 16 + c16];
        Gi2[g].x = gv; Gi2[g].y = gv;
    }

    f32x4 acc[2][4] = {};
    f32x4 den[2] = {};
    const bf16x8 ones = {0x3F80, 0x3F80, 0x3F80, 0x3F80,
                         0x3F80, 0x3F80, 0x3F80, 0x3F80};
    const ushort* WhtB = Wht_t + (size_t)bh * 32 * 4096;   // 32 tiles x 4096 ushorts
    const float* Eb = Ee + (size_t)bh * N_;
    const float* Fb = Ff + (size_t)bh * N_;

    // stage tile 0 into buf 0 (async)
    {
        const char* gt = (const char*)(WhtB);
        #pragma unroll
        for (int q = 0; q < 2; q++)
            glds16(gt + wid * 2048 + q * 1024 + lane * 16,
                   (char*)&Whs[0][0] + wid * 2048 + q * 1024);
        if (wid == 0) {
            glds4(Eb + lane, &E_s[0][0]);
            glds4(Fb + lane, &F_s[0][0]);
        }
    }

    for (int jt = 0; jt < 32; jt++) {
        const int buf = jt & 1;
        __syncthreads();                        // drains glds -> tile jt resident
        if (jt < 31) {                          // issue next tile (lands during consume)
            const int nb_ = buf ^ 1;
            const char* gt = (const char*)(WhtB + (size_t)(jt + 1) * 4096);
            #pragma unroll
            for (int q = 0; q < 2; q++)
                glds16(gt + wid * 2048 + q * 1024 + lane * 16,
                       (char*)&Whs[nb_][0] + wid * 2048 + q * 1024);
            if (wid == 0) {
                glds4(Eb + (jt + 1) * 64 + lane, &E_s[nb_][0]);
                glds4(Fb + (jt + 1) * 64 + lane, &F_s[nb_][0]);
            }
        }
        #pragma unroll
        for (int ks = 0; ks < 2; ks++) {
            const int jb = ks * 32 + quad * 8;
            f32x2 e2[4], f2[4];
            {
                float4 e0 = *(const float4*)&E_s[buf][jb];
                float4 e1 = *(const float4*)&E_s[buf][jb + 4];
                float4 f0 = *(const float4*)&F_s[buf][jb];
                float4 f1 = *(const float4*)&F_s[buf][jb + 4];
                e2[0].x = e0.x; e2[0].y = e0.y; e2[1].x = e0.z; e2[1].y = e0.w;
                e2[2].x = e1.x; e2[2].y = e1.y; e2[3].x = e1.z; e2[3].y = e1.w;
                f2[0].x = f0.x; f2[0].y = f0.y; f2[1].x = f0.z; f2[1].y = f0.w;
                f2[2].x = f1.x; f2[2].y = f1.y; f2[3].x = f1.z; f2[3].y = f1.w;
            }
            const int cjs = (ks * 4 + quad) ^ (c16 & 7);   // swizzled chunk
            bf16x8 bfr[4];
            #pragma unroll
            for (int fd = 0; fd < 4; fd++)
                bfr[fd] = *(const bf16x8*)&Whs[buf][(fd * 16 + c16) * 64 + cjs * 8];
            #pragma unroll
            for (int g = 0; g < 2; g++) {
                union { bf16x8 v; uint u[4]; } af;
                #pragma unroll
                for (int jp = 0; jp < 4; jp++) {
                    f32x2 q2 = __builtin_elementwise_max(e2[jp], Gi2[g] * f2[jp]);
                    uint a = __float_as_uint(q2.x) + 0x8000u;
                    uint bq = __float_as_uint(q2.y) + 0x8000u;
                    af.u[jp] = __builtin_amdgcn_perm(bq, a, 0x07060302u);
                }
                #pragma unroll
                for (int fd = 0; fd < 4; fd++)
                    acc[g][fd] = __builtin_amdgcn_mfma_f32_16x16x32_bf16(af.v, bfr[fd], acc[g][fd], 0, 0, 0);
                den[g] = __builtin_amdgcn_mfma_f32_16x16x32_bf16(af.v, ones, den[g], 0, 0, 0);
            }
        }
    }

    float bl[4];
    #pragma unroll
    for (int fd = 0; fd < 4; fd++) bl[fd] = bias[hh * 64 + fd * 16 + c16];
    #pragma unroll
    for (int g = 0; g < 2; g++)
        #pragma unroll
        for (int r = 0; r < 4; r++) {
            int i = ibase + g * 16 + quad * 4 + r;
            float inv = 1.0f / den[g][r];
            float* dst = out + (size_t)(b * N_ + i) * C_ + hh * 64;
            #pragma unroll
            for (int fd = 0; fd < 4; fd++)
                dst[fd * 16 + c16] = acc[g][fd][r] * inv + bl[fd];
        }
}

// ---------------------------------------------------------------------------
extern "C" void kernel_launch(void* const* d_in, const int* in_sizes, int n_in,
                              void* d_out, int out_size, void* d_ws, size_t ws_size,
                              hipStream_t stream) {
    const float* h     = (const float*)d_in[0];
    const float* W     = (const float*)d_in[1];
    const float* a_src = (const float*)d_in[2];
    const float* a_dst = (const float*)d_in[3];
    const float* bias  = (const float*)d_in[4];
    float* out = (float*)d_out;

    ushort* Wt_hi = (ushort*)d_ws;                       // 256*256
    ushort* Wt_lo = Wt_hi + 256 * 256;
    ushort* Wht_t = Wt_lo + 256 * 256;                   // M_*C_ bf16, tile-major swizzled
    float*  Ee    = (float*)(Wht_t + (size_t)M_ * C_);   // 32*2048
    float*  Ff    = Ee + 32 * N_;
    float*  Gg    = Ff + 32 * N_;

    wprep_kernel<<<64, 256, 0, stream>>>(W, Wt_hi, Wt_lo);
    gemm_fused<<<dim3(M_ / 128, 4), 256, 0, stream>>>(h, Wt_hi, Wt_lo, a_src, a_dst,
                                                      Wht_t, Ee, Ff, Gg);
    attn_kernel<<<dim3(32, 16), 256, 0, stream>>>(Wht_t, Ee, Ff, Gg, bias, out);
}